// Round 12
// baseline (74.143 us; speedup 1.0000x reference)
//
#include <hip/hip_runtime.h>

#define NPTS 16384
#define NNBR 32
#define CIN 16
#define COUT 16
#define NBASIS 16

// LDS f16 row stride 264 (528 B = 132 dw ≡ 4 mod 32): b128 reads alias 2-way (free).
#define WF_OS 264
#define ML_PS 264

// sqrt(10 * log2(e)) : exp(-10 d^2) == exp2(-(SCL*d)^2)
#define RSCL 3.7982825f

typedef _Float16 half8 __attribute__((ext_vector_type(8)));
typedef _Float16 half4 __attribute__((ext_vector_type(4)));
typedef unsigned short ushort8 __attribute__((ext_vector_type(8)));
typedef float floatx4 __attribute__((ext_vector_type(4)));

// ws layout (f16 units): [0, NPTS*16) xT16 [n][i] ; then Wf16 [o][b*16+i]
#define WS_XT 0
#define WS_WF (NPTS * CIN)

// Prep: 256 blocks x 256 threads (R6-identical, proven).
__global__ __launch_bounds__(256) void prep_kernel(
        const float* __restrict__ input, const float* __restrict__ W,
        _Float16* __restrict__ ws) {
    const int p4 = threadIdx.x >> 2;          // 0..63 point within block
    const int c4 = threadIdx.x & 3;           // channel quad
    const int n = blockIdx.x * 64 + p4;
    half4 v;
    #pragma unroll
    for (int j = 0; j < 4; ++j)
        v[j] = (_Float16)input[(c4 * 4 + j) * NPTS + n];
    *(half4*)&ws[WS_XT + n * CIN + c4 * 4] = v;
    if (blockIdx.x == 0) {   // W -> [o][b*16+i] f16
        const int o = threadIdx.x >> 4, b = threadIdx.x & 15;
        _Float16 w[16];
        #pragma unroll
        for (int i = 0; i < CIN; ++i) w[i] = (_Float16)W[o * 256 + i * 16 + b];
        *(half8*)&ws[WS_WF + o * 256 + b * 16]     = *(half8*)&w[0];
        *(half8*)&ws[WS_WF + o * 256 + b * 16 + 8] = *(half8*)&w[8];
    }
}

// Conv: 2048 blocks x 256 = 8 points/block, 8 blocks/CU x 4 waves = 32
// waves/CU. R6 single-barrier body + L2-WARM PROLOGUE:
// The harness's 268 MB poison fill evicts L2/L3 every iteration, so conv's
// random gathers (coords[nbr], xT16[nbv]) fault the ~720 KB gather set into
// each XCD's L2 via dependent scattered ~900-cyc misses (MSHR-limited,
// ~19 us -- the cold-vs-warm gap measured by the R9 REPS probe). The
// prologue instead STREAMS the gather set coalesced: each block reads a
// ~2.8 KB slice (slice-hash covers all 256 slices per XCD under either
// round-robin or contiguous block->XCD mapping), keep-alive via asm so it
// isn't DCE'd. By the time the dependent gather chain reaches L2, lines are
// resident (L2-hit ~200 cyc).
__global__ __launch_bounds__(256, 8) void se3_conv_kernel(
        const _Float16* __restrict__ ws,
        const float* __restrict__ coords,    // (NPTS, 3)
        const float* __restrict__ centers,   // (NBASIS,)
        const float* __restrict__ mask,      // (NPTS, NNBR) f32
        const int* __restrict__ neighbors,   // (NPTS, NNBR)
        float* __restrict__ out) {           // (COUT, NPTS)
    __shared__ _Float16 Wf[COUT * WF_OS];        // 8448 B
    __shared__ _Float16 Mld[8 * ML_PS];          // 4224 B
    __shared__ float    rs[8 * NNBR];            // 1024 B  (pre-scaled RSCL)
    __shared__ unsigned short nb16[8 * NNBR];    //  512 B
    __shared__ _Float16 mv16[8 * NNBR];          //  512 B

    const _Float16* xT16 = &ws[WS_XT];

    const int tid = threadIdx.x;
    const int t = tid & 15;          // lane role (i in B / o in C)
    const int quad = (tid >> 4) & 3; // k-chunk select
    const int wv = tid >> 6;         // wave 0..3
    const int nbase = blockIdx.x * 8;

    // ---- L2-warm prologue: issued before anything else so the streaming
    // fill overlaps the dependent-miss chain below. 176 coalesced dwordx4
    // per block (xT16: 128, coords: 48).
    {
        const int b = blockIdx.x;
        const int slice = ((b >> 3) ^ ((b & 7) << 5)) & 255;
        if (tid < 128) {
            const float* xf = (const float*)xT16;
            const float4 p = *(const float4*)&xf[slice * 512 + tid * 4];
            asm volatile("" :: "v"(p.x), "v"(p.y), "v"(p.z), "v"(p.w));
        } else if (tid < 176) {
            const float4 p =
                *(const float4*)&coords[slice * 192 + (tid - 128) * 4];
            asm volatile("" :: "v"(p.x), "v"(p.y), "v"(p.z), "v"(p.w));
        }
    }

    // ---- Phase A loads: one (pt,k) pair per thread. pt = tid>>5, k = tid&31.
    const int pt = tid >> 5;
    const int k = tid & 31;
    const int n = nbase + pt;
    const int nbr = neighbors[n * NNBR + k] & (NPTS - 1);
    const float m = mask[n * NNBR + k];
    const float nx = coords[n * 3 + 0], ny = coords[n * 3 + 1],
                nz = coords[n * 3 + 2];
    const float bx = coords[nbr * 3 + 0], by = coords[nbr * 3 + 1],
                bz = coords[nbr * 3 + 2];

    // ---- Stage Wf while phase-A loads are in flight (consumed in phase C).
    {
        const int o = tid >> 4, ch = tid & 15;
        const half8 w0 = *(const half8*)&ws[WS_WF + o * 256 + ch * 16];
        const half8 w1 = *(const half8*)&ws[WS_WF + o * 256 + ch * 16 + 8];
        *(half8*)&Wf[o * WF_OS + ch * 16]     = w0;
        *(half8*)&Wf[o * WF_OS + ch * 16 + 8] = w1;
    }

    // ---- Phase A compute + intra-wave LDS publish (lgkmcnt orders the
    // same-wave ds_write -> ds_read; no block barrier needed).
    {
        const float dx = bx - nx, dy = by - ny, dz = bz - nz;
        rs[pt * NNBR + k] =
            sqrtf(dx * dx + dy * dy + dz * dz + 1e-12f) * RSCL;
        nb16[pt * NNBR + k] = (unsigned short)nbr;
        mv16[pt * NNBR + k] = (_Float16)m;
    }

    // ---- Phase B (pre-barrier): wave wv -> points 2wv, 2wv+1; one
    // mfma_16x16x32_f16 each.
    // A[m=i=t][k=8q+j] = x[nbr][t]*mask ; B[k][n=b=t] = exp2(-(rscl-c_t)^2)
    const float cs = centers[t] * RSCL;
    const int kb0 = (wv * 2 + 0) * NNBR + 8 * quad;  // group-broadcast LDS
    const int kb1 = (wv * 2 + 1) * NNBR + 8 * quad;
    const ushort8 nbv0 = *(const ushort8*)&nb16[kb0];
    const ushort8 nbv1 = *(const ushort8*)&nb16[kb1];
    const half8 mvv0 = *(const half8*)&mv16[kb0];
    const half8 mvv1 = *(const half8*)&mv16[kb1];
    const float4 r00 = *(const float4*)&rs[kb0];
    const float4 r01 = *(const float4*)&rs[kb0 + 4];
    const float4 r10 = *(const float4*)&rs[kb1];
    const float4 r11 = *(const float4*)&rs[kb1 + 4];

    // All 16 x-gathers issued before exp work; L2-hit after the warm.
    half8 xh0, xh1;
    #pragma unroll
    for (int j = 0; j < 8; ++j) xh0[j] = xT16[(int)nbv0[j] * CIN + t];
    #pragma unroll
    for (int j = 0; j < 8; ++j) xh1[j] = xT16[(int)nbv1[j] * CIN + t];

    const float rj0[8] = {r00.x, r00.y, r00.z, r00.w, r01.x, r01.y, r01.z, r01.w};
    const float rj1[8] = {r10.x, r10.y, r10.z, r10.w, r11.x, r11.y, r11.z, r11.w};

    {   // q = 0
        half8 af, bf;
        #pragma unroll
        for (int j = 0; j < 8; ++j) {
            const float d = rj0[j] - cs;
            // v_exp_f32 is exp2 natively; negate folds into the src modifier.
            bf[j] = (_Float16)__builtin_amdgcn_exp2f(-(d * d));
        }
        af = xh0 * mvv0;                           // v_pk_mul_f16, no cvt chain
        floatx4 c = {0.0f, 0.0f, 0.0f, 0.0f};
        c = __builtin_amdgcn_mfma_f32_16x16x32_f16(af, bf, c, 0, 0, 0);
        _Float16 h[4];
        #pragma unroll
        for (int v = 0; v < 4; ++v) h[v] = (_Float16)c[v];
        // D[row=i=4quad+v][col=b=t] -> Mld[pq][t*16 + 4quad + v] (one b64)
        *(uint2*)&Mld[(wv * 2 + 0) * ML_PS + t * 16 + 4 * quad] = *(uint2*)h;
    }
    {   // q = 1
        half8 af, bf;
        #pragma unroll
        for (int j = 0; j < 8; ++j) {
            const float d = rj1[j] - cs;
            bf[j] = (_Float16)__builtin_amdgcn_exp2f(-(d * d));
        }
        af = xh1 * mvv1;
        floatx4 c = {0.0f, 0.0f, 0.0f, 0.0f};
        c = __builtin_amdgcn_mfma_f32_16x16x32_f16(af, bf, c, 0, 0, 0);
        _Float16 h[4];
        #pragma unroll
        for (int v = 0; v < 4; ++v) h[v] = (_Float16)c[v];
        *(uint2*)&Mld[(wv * 2 + 1) * ML_PS + t * 16 + 4 * quad] = *(uint2*)h;
    }

    __syncthreads();   // the ONLY barrier: {Wf, Mld} -> phase C

    // ---- Phase C (every wave, redundant): Out = W(16x256) * Mflat(256x8).
    // A[m=o=t][bi-chunk]; B[bi-chunk][n=pt=t] valid for t<8 (cols 8-15 zero).
    floatx4 acc = {0.0f, 0.0f, 0.0f, 0.0f};
    #pragma unroll
    for (int cch = 0; cch < 8; ++cch) {
        const int bi = cch * 32 + 8 * quad;
        const half8 a = *(const half8*)&Wf[t * WF_OS + bi];
        half8 b = {};
        if (t < 8) b = *(const half8*)&Mld[t * ML_PS + bi];
        acc = __builtin_amdgcn_mfma_f32_16x16x32_f16(a, b, acc, 0, 0, 0);
    }
    // D[row=o=4quad+v][col=pt=t]; wave wv stores cols 2wv, 2wv+1.
    if (t < 8 && wv == (t >> 1)) {
        #pragma unroll
        for (int v = 0; v < 4; ++v)
            out[(4 * quad + v) * NPTS + nbase + t] = acc[v];
    }
}

extern "C" void kernel_launch(void* const* d_in, const int* in_sizes, int n_in,
                              void* d_out, int out_size, void* d_ws, size_t ws_size,
                              hipStream_t stream) {
    const float* input   = (const float*)d_in[0];
    const float* coords  = (const float*)d_in[1];
    const float* W       = (const float*)d_in[2];
    const float* centers = (const float*)d_in[3];
    const float* mask    = (const float*)d_in[4];
    const int*   nbr     = (const int*)d_in[5];
    float* out = (float*)d_out;
    _Float16* ws = (_Float16*)d_ws;   // ~520 KB of the 256 MB workspace

    prep_kernel<<<NPTS / 64, 256, 0, stream>>>(input, W, ws);
    se3_conv_kernel<<<NPTS / 8, 256, 0, stream>>>(ws, coords, centers, mask,
                                                  nbr, out);
}